// Round 4
// baseline (156.766 us; speedup 1.0000x reference)
//
#include <hip/hip_runtime.h>
#include <hip/hip_bf16.h>
#include <cfloat>
#include <math.h>

#define N_NODES 8192
#define M_EDGES 2048
#define D_IN    256
#define DH      8
#define NODE_CAP 32    // max edges per node; deg mean 8.2, std 2.9 -> 8.5 sigma margin
#define EDGE_CAP 128   // max nodes per edge; mean 32.8, std 5.7 -> 16 sigma margin
#define EMPTY_CAP 16   // expected ~2.3 empty nodes, ~0 empty edges
#define SCAN_BLOCKS (N_NODES / 4)                    // 2048
#define PROJ_BLOCKS ((N_NODES + M_EDGES) / 4)        // 2560

__device__ __forceinline__ float wave_reduce_sum(float v) {
    #pragma unroll
    for (int m = 1; m < 64; m <<= 1) v += __shfl_xor(v, m, 64);
    return v;
}
__device__ __forceinline__ float wave_reduce_max(float v) {
    #pragma unroll
    for (int m = 1; m < 64; m <<= 1) v = fmaxf(v, __shfl_xor(v, m, 64));
    return v;
}
__device__ __forceinline__ float leaky(float t) { return t >= 0.f ? t : 0.2f * t; }
__device__ __forceinline__ float elu(float v) { return v > 0.f ? v : expm1f(v); }

// Kernel A: fused scan (blocks < SCAN_BLOCKS) || proj (remaining blocks).
// No cross-phase dependency; no workspace initialization required anywhere:
// counters tolerate arbitrary initial values (slot = atomicAdd return mod CAP),
// list validity is by value-range check (0xAAAAAAAA poison is invalid).
__global__ __launch_bounds__(256) void fused_front(
    const float* __restrict__ H,
    const float* __restrict__ X, const float* __restrict__ E,
    const float* __restrict__ W, const float* __restrict__ ax, const float* __restrict__ ae,
    float* __restrict__ WX,
    float* __restrict__ sx, float* __restrict__ se,
    float* __restrict__ s1, float* __restrict__ s2,
    int* __restrict__ node_cnt, int* __restrict__ node_list,
    unsigned* __restrict__ edge_ctr, int* __restrict__ edge_list,
    unsigned* __restrict__ empty_node_ctr, int* __restrict__ empty_node_list) {
    if (blockIdx.x < SCAN_BLOCKS) {
        // ---- scan phase: H row -> node_list/node_cnt + transposed edge_list ----
        __shared__ int s_cnt[4];
        __shared__ int s_list[4][NODE_CAP];
        int wv = threadIdx.x >> 6, lane = threadIdx.x & 63;
        int i = blockIdx.x * 4 + wv;
        if (lane == 0) s_cnt[wv] = 0;
        __syncthreads();
        const float4* Hrow = (const float4*)(H + (size_t)i * M_EDGES);
        float4 v[8];
        #pragma unroll
        for (int it = 0; it < 8; ++it) v[it] = Hrow[it * 64 + lane];
        #pragma unroll
        for (int it = 0; it < 8; ++it) {
            int c0 = (it * 64 + lane) * 4;
            if (v[it].x > 0.f) { int p = atomicAdd(&s_cnt[wv], 1); if (p < NODE_CAP) s_list[wv][p] = c0; }
            if (v[it].y > 0.f) { int p = atomicAdd(&s_cnt[wv], 1); if (p < NODE_CAP) s_list[wv][p] = c0 + 1; }
            if (v[it].z > 0.f) { int p = atomicAdd(&s_cnt[wv], 1); if (p < NODE_CAP) s_list[wv][p] = c0 + 2; }
            if (v[it].w > 0.f) { int p = atomicAdd(&s_cnt[wv], 1); if (p < NODE_CAP) s_list[wv][p] = c0 + 3; }
        }
        __syncthreads();
        int cnt = min(s_cnt[wv], NODE_CAP);
        if (lane == 0) node_cnt[i] = cnt;
        if (cnt == 0) {
            if (lane == 0) {
                unsigned p = atomicAdd(empty_node_ctr, 1u);
                empty_node_list[p & (EMPTY_CAP - 1)] = i;
            }
            return;
        }
        if (lane < cnt) {
            int k = s_list[wv][lane];
            node_list[i * NODE_CAP + lane] = k;
            unsigned p = atomicAdd(&edge_ctr[k], 1u);
            edge_list[k * EDGE_CAP + (int)(p & (EDGE_CAP - 1))] = i;
        }
        return;
    }
    // ---- proj phase: WX = X@W (stored); WE = E@W (not stored); scalar scores ----
    int b = blockIdx.x - SCAN_BLOCKS;
    int wave = (b * 256 + (int)threadIdx.x) >> 6;   // 0 .. N+M-1
    int lane = threadIdx.x & 63;
    bool isX = wave < N_NODES;
    int row = isX ? wave : wave - N_NODES;
    const float* src = isX ? (X + (size_t)row * D_IN) : (E + (size_t)row * D_IN);
    float4 x4 = ((const float4*)src)[lane];
    const float4* W4 = (const float4*)W;
    float4 w[8];
    #pragma unroll
    for (int j = 0; j < 8; j++) w[j] = W4[lane * 8 + j];   // W rows 4l..4l+3 (contiguous)
    const float* wf = (const float*)w;
    float wxd[DH];
    #pragma unroll
    for (int d = 0; d < DH; d++) {
        float p = x4.x * wf[d] + x4.y * wf[8 + d] + x4.z * wf[16 + d] + x4.w * wf[24 + d];
        wxd[d] = wave_reduce_sum(p);
    }
    if (lane == 0) {
        if (isX) {
            float a0 = 0.f, a1 = 0.f;
            #pragma unroll
            for (int d = 0; d < DH; d++) {
                WX[row * DH + d] = wxd[d];
                a0 += wxd[d] * ax[d];        // sx
                a1 += wxd[d] * ae[DH + d];   // s2
            }
            sx[row] = a0; s2[row] = a1;
        } else {
            float a0 = 0.f, a1 = 0.f;
            #pragma unroll
            for (int d = 0; d < DH; d++) {
                a0 += wxd[d] * ax[DH + d];   // se
                a1 += wxd[d] * ae[d];        // s1
            }
            se[row] = a0; s1[row] = a1;
        }
    }
}

// Kernel C: per-edge gather. Recomputes pass-1 softmax denom per member on the fly
// (node_list rows are contiguous, se is L1/L2-resident). Also pass-2 stats + empty-edge list.
__global__ __launch_bounds__(256) void edge_gather_kernel(
    const int* __restrict__ edge_list,
    const float* __restrict__ WX,
    const float* __restrict__ sx, const float* __restrict__ se,
    const float* __restrict__ s1, const float* __restrict__ s2,
    const int* __restrict__ node_cnt, const int* __restrict__ node_list,
    const int* __restrict__ empty_node_list,
    float* __restrict__ E_new, float* __restrict__ edge_m2, float* __restrict__ edge_inv2,
    unsigned* __restrict__ empty_edge_ctr, int* __restrict__ empty_edge_list) {
    int wv = threadIdx.x >> 6, lane = threadIdx.x & 63;
    int k = blockIdx.x * 4 + wv;
    float sek = se[k], s1k = s1[k];

    // lane 0: sum WX over empty nodes (valid ids < N; poison fails the check)
    float ex[DH];
    #pragma unroll
    for (int d = 0; d < DH; d++) ex[d] = 0.f;
    if (lane == 0) {
        for (int j = 0; j < EMPTY_CAP; ++j) {
            int id = empty_node_list[j];
            if ((unsigned)id < (unsigned)N_NODES) {
                #pragma unroll
                for (int d = 0; d < DH; d++) ex[d] += WX[id * DH + d];
            }
        }
    }

    int e0 = edge_list[k * EDGE_CAP + lane];
    int e1 = edge_list[k * EDGE_CAP + 64 + lane];
    bool v0 = (unsigned)e0 < (unsigned)N_NODES;
    bool v1 = (unsigned)e1 < (unsigned)N_NODES;
    int cnt = __popcll(__ballot(v0)) + __popcll(__ballot(v1));

    float acc[DH];
    #pragma unroll
    for (int d = 0; d < DH; d++) acc[d] = 0.f;
    float lg0 = -FLT_MAX, lg1 = -FLT_MAX;

    #pragma unroll
    for (int s = 0; s < 2; ++s) {
        bool vv = s == 0 ? v0 : v1;
        int ii = s == 0 ? e0 : e1;
        if (vv) {
            float sxi = sx[ii];
            int ci = node_cnt[ii];                 // >= 1 (ii is a member of edge k)
            const int4* nl4 = (const int4*)(node_list + ii * NODE_CAP);
            int4 nv[NODE_CAP / 4];
            int nq = (ci + 3) >> 2;
            for (int t = 0; t < nq; ++t) nv[t] = nl4[t];   // independent loads in flight
            const int* nls = (const int*)nv;
            float denom = 0.f;
            for (int t = 0; t < ci; ++t) denom += expf(leaky(sxi + se[nls[t]]));
            float wgt = expf(leaky(sxi + sek)) / denom;
            #pragma unroll
            for (int d = 0; d < DH; d++) acc[d] += wgt * WX[ii * DH + d];
            float lg = leaky(s1k + s2[ii]);
            if (s == 0) lg0 = lg; else lg1 = lg;
        }
    }
    #pragma unroll
    for (int d = 0; d < DH; d++) acc[d] = wave_reduce_sum(acc[d]);
    float m2 = wave_reduce_max(fmaxf(lg0, lg1));
    float e2 = (v0 ? expf(lg0 - m2) : 0.f) + (v1 ? expf(lg1 - m2) : 0.f);
    float sum2 = wave_reduce_sum(e2);
    if (lane == 0) {
        #pragma unroll
        for (int d = 0; d < DH; d++)
            E_new[k * DH + d] = elu(acc[d] + ex[d] * (1.0f / (float)M_EDGES));
        if (cnt == 0) {
            unsigned p = atomicAdd(empty_edge_ctr, 1u);
            empty_edge_list[p & (EMPTY_CAP - 1)] = k;
        } else {
            edge_m2[k] = m2; edge_inv2[k] = 1.f / sum2;
        }
    }
}

// Kernel D: per-node gather; 8 lanes per node (one per dim).
__global__ __launch_bounds__(256) void node_gather_kernel(
    const int* __restrict__ node_cnt, const int* __restrict__ node_list,
    const float* __restrict__ s1, const float* __restrict__ s2,
    const float* __restrict__ edge_m2, const float* __restrict__ edge_inv2,
    const float* __restrict__ E_new, const int* __restrict__ empty_edge_list,
    float* __restrict__ out) {
    int idx = blockIdx.x * blockDim.x + threadIdx.x;   // 65536 threads
    int i = idx >> 3, d = idx & 7;
    // empty-edge uniform contribution: sum E_new over empty edges / N
    float acc = 0.f;
    for (int j = 0; j < EMPTY_CAP; ++j) {
        int kk = empty_edge_list[j];
        if ((unsigned)kk < (unsigned)M_EDGES) acc += E_new[kk * DH + d];
    }
    acc *= (1.0f / (float)N_NODES);
    int cnt = node_cnt[i];
    float s2i = s2[i];
    for (int e = 0; e < cnt; ++e) {
        int k = node_list[i * NODE_CAP + e];
        float w2 = expf(leaky(s1[k] + s2i) - edge_m2[k]) * edge_inv2[k];
        acc += w2 * E_new[k * DH + d];
    }
    out[i * DH + d] = elu(acc);
}

extern "C" void kernel_launch(void* const* d_in, const int* in_sizes, int n_in,
                              void* d_out, int out_size, void* d_ws, size_t ws_size,
                              hipStream_t stream) {
    const float* X  = (const float*)d_in[0];
    const float* E  = (const float*)d_in[1];
    const float* H  = (const float*)d_in[2];
    const float* W  = (const float*)d_in[3];
    const float* ax = (const float*)d_in[4];
    const float* ae = (const float*)d_in[5];
    float* out = (float*)d_out;

    float* ws = (float*)d_ws;
    // workspace layout (float offsets) — NO region requires initialization
    float* WX        = ws + 0;        // 65536
    float* sx        = ws + 65536;    // 8192
    float* se        = ws + 73728;    // 2048
    float* s1        = ws + 75776;    // 2048
    float* s2        = ws + 77824;    // 8192
    float* E_new     = ws + 86016;    // 16384
    float* edge_m2   = ws + 102400;   // 2048
    float* edge_inv2 = ws + 104448;   // 2048
    int*   node_cnt  = (int*)(ws + 106496);   // 8192
    int*   node_list = (int*)(ws + 114688);   // 8192*32 (16B-aligned base)
    unsigned* edge_ctr  = (unsigned*)(ws + 376832);  // 2048 (any init OK)
    int*   edge_list = (int*)(ws + 378880);   // 2048*128
    unsigned* empty_node_ctr  = (unsigned*)(ws + 641024); // 1
    int*   empty_node_list    = (int*)(ws + 641025);      // 16
    unsigned* empty_edge_ctr  = (unsigned*)(ws + 641041); // 1
    int*   empty_edge_list    = (int*)(ws + 641042);      // 16
    // total 641058 floats = 2.45 MB

    fused_front<<<SCAN_BLOCKS + PROJ_BLOCKS, 256, 0, stream>>>(
        H, X, E, W, ax, ae, WX, sx, se, s1, s2,
        node_cnt, node_list, edge_ctr, edge_list,
        empty_node_ctr, empty_node_list);
    edge_gather_kernel<<<M_EDGES / 4, 256, 0, stream>>>(
        edge_list, WX, sx, se, s1, s2, node_cnt, node_list, empty_node_list,
        E_new, edge_m2, edge_inv2, empty_edge_ctr, empty_edge_list);
    node_gather_kernel<<<(N_NODES * DH) / 256, 256, 0, stream>>>(
        node_cnt, node_list, s1, s2, edge_m2, edge_inv2, E_new, empty_edge_list, out);
}

// Round 5
// 140.688 us; speedup vs baseline: 1.1143x; 1.1143x over previous
//
#include <hip/hip_runtime.h>
#include <hip/hip_bf16.h>
#include <cfloat>
#include <math.h>

#define N_NODES 8192
#define M_EDGES 2048
#define D_IN    256
#define DH      8
#define NODE_CAP 32    // max edges per node; deg mean 8.2, std 2.9 -> 8.5 sigma margin
#define EDGE_CAP 128   // max nodes per edge; mean 32.8, std 5.7 -> 16 sigma margin
#define PROJ_BLOCKS ((N_NODES + M_EDGES) / 4)
#define ZERO_INTS (M_EDGES + 16)          // edge_cnt + emptyX + emptyE (contiguous)
#define ZERO_BLOCKS 9

__device__ __forceinline__ float wave_reduce_sum(float v) {
    #pragma unroll
    for (int m = 1; m < 64; m <<= 1) v += __shfl_xor(v, m, 64);
    return v;
}
__device__ __forceinline__ float wave_reduce_max(float v) {
    #pragma unroll
    for (int m = 1; m < 64; m <<= 1) v = fmaxf(v, __shfl_xor(v, m, 64));
    return v;
}
__device__ __forceinline__ float leaky(float t) { return t >= 0.f ? t : 0.2f * t; }
__device__ __forceinline__ float elu(float v) { return v > 0.f ? v : expm1f(v); }

// Kernel 1: WX = X@W, WE = E@W (scores only), plus scalar scores.
// Tail blocks zero edge_cnt/emptyX/emptyE (no separate memset dispatch).
__global__ __launch_bounds__(256) void proj_kernel(
    const float* __restrict__ X, const float* __restrict__ E,
    const float* __restrict__ W, const float* __restrict__ ax, const float* __restrict__ ae,
    float* __restrict__ WX,
    float* __restrict__ sx, float* __restrict__ se,
    float* __restrict__ s1, float* __restrict__ s2,
    int* __restrict__ zero_region) {
    if (blockIdx.x >= PROJ_BLOCKS) {
        int z = (blockIdx.x - PROJ_BLOCKS) * 256 + threadIdx.x;
        if (z < ZERO_INTS) zero_region[z] = 0;
        return;
    }
    int wave = (blockIdx.x * blockDim.x + threadIdx.x) >> 6;
    int lane = threadIdx.x & 63;
    bool isX = wave < N_NODES;
    int row = isX ? wave : wave - N_NODES;
    const float* src = isX ? (X + (size_t)row * D_IN) : (E + (size_t)row * D_IN);
    float4 x4 = ((const float4*)src)[lane];
    const float4* W4 = (const float4*)W;
    float4 w[8];
    #pragma unroll
    for (int j = 0; j < 8; j++) w[j] = W4[lane * 8 + j];   // W rows 4l..4l+3 (contiguous)
    const float* wf = (const float*)w;
    float wxd[DH];
    #pragma unroll
    for (int d = 0; d < DH; d++) {
        float p = x4.x * wf[d] + x4.y * wf[8 + d] + x4.z * wf[16 + d] + x4.w * wf[24 + d];
        wxd[d] = wave_reduce_sum(p);
    }
    if (lane == 0) {
        if (isX) {
            float a0 = 0.f, a1 = 0.f;
            #pragma unroll
            for (int d = 0; d < DH; d++) {
                WX[row * DH + d] = wxd[d];
                a0 += wxd[d] * ax[d];        // sx
                a1 += wxd[d] * ae[DH + d];   // s2
            }
            sx[row] = a0; s2[row] = a1;
        } else {
            float a0 = 0.f, a1 = 0.f;
            #pragma unroll
            for (int d = 0; d < DH; d++) {
                a0 += wxd[d] * ax[DH + d];   // se
                a1 += wxd[d] * ae[d];        // s1
            }
            se[row] = a0; s1[row] = a1;
        }
    }
}

// Kernel 2: per-node scan of H row via ballot compaction (no LDS, no barriers).
// Builds node->edge list, per-node softmax denom (no max-sub: |logit|<~30, f32-safe),
// transposed edge lists (counter atomics only), empty-node accumulation.
__global__ __launch_bounds__(256) void node_scan_kernel(
    const float* __restrict__ H, const float* __restrict__ WX,
    const float* __restrict__ sx, const float* __restrict__ se,
    int* __restrict__ node_cnt, int* __restrict__ node_list,
    float* __restrict__ node_inv,
    int* __restrict__ edge_cnt, int* __restrict__ edge_list,
    float* __restrict__ emptyX) {
    int wv = threadIdx.x >> 6, lane = threadIdx.x & 63;
    int i = blockIdx.x * 4 + wv;
    const float4* Hrow = (const float4*)(H + (size_t)i * M_EDGES);
    float4 v[8];
    #pragma unroll
    for (int it = 0; it < 8; ++it) v[it] = Hrow[it * 64 + lane];   // all loads in flight
    float sxi = sx[i];
    unsigned long long ltmask = (1ull << lane) - 1ull;
    int base = 0;
    float esum = 0.f;
    #pragma unroll
    for (int it = 0; it < 8; ++it) {
        #pragma unroll
        for (int c = 0; c < 4; ++c) {
            float hv = (c == 0) ? v[it].x : (c == 1) ? v[it].y : (c == 2) ? v[it].z : v[it].w;
            bool set = hv > 0.f;
            unsigned long long m = __ballot(set);
            if (set) {
                int k = (it * 64 + lane) * 4 + c;
                int pos = base + __popcll(m & ltmask);
                if (pos < NODE_CAP) node_list[i * NODE_CAP + pos] = k;
                esum += expf(leaky(sxi + se[k]));
                int p = atomicAdd(&edge_cnt[k], 1);
                if (p < EDGE_CAP) edge_list[k * EDGE_CAP + p] = i;
            }
            base += __popcll(m);
        }
    }
    if (base == 0) {
        // all-NEG_INF row -> uniform 1/M over every edge; accumulate WX[i]
        if (lane == 0) node_cnt[i] = 0;
        if (lane < DH) atomicAdd(&emptyX[lane], WX[i * DH + lane]);
        return;
    }
    float s = wave_reduce_sum(esum);
    if (lane == 0) {
        node_cnt[i] = min(base, NODE_CAP);
        node_inv[i] = 1.f / s;
    }
}

// Kernel 3: per-edge gather. E_new[k] = elu(sum_i att[i,k]*WX[i] + emptyX/M).
// Also pass-2 softmax stats (m2_k, inv2_k) over the same member list.
__global__ __launch_bounds__(256) void edge_gather_kernel(
    const int* __restrict__ edge_cnt, const int* __restrict__ edge_list,
    const float* __restrict__ WX,
    const float* __restrict__ sx, const float* __restrict__ se,
    const float* __restrict__ s1, const float* __restrict__ s2,
    const float* __restrict__ node_inv,
    const float* __restrict__ emptyX,
    float* __restrict__ E_new, float* __restrict__ edge_m2, float* __restrict__ edge_inv2,
    float* __restrict__ emptyE) {
    int wv = threadIdx.x >> 6, lane = threadIdx.x & 63;
    int k = blockIdx.x * 4 + wv;
    int cnt = min(edge_cnt[k], EDGE_CAP);
    float sek = se[k], s1k = s1[k];
    float acc[DH];
    #pragma unroll
    for (int d = 0; d < DH; d++) acc[d] = 0.f;
    float lg2_0 = -FLT_MAX, lg2_1 = -FLT_MAX;
    bool h0 = lane < cnt, h1 = lane + 64 < cnt;
    if (h0) {
        int i0 = edge_list[k * EDGE_CAP + lane];
        float w = expf(leaky(sx[i0] + sek)) * node_inv[i0];
        const float4* wx4 = (const float4*)(WX + i0 * DH);
        float4 a = wx4[0], b = wx4[1];
        acc[0] += w * a.x; acc[1] += w * a.y; acc[2] += w * a.z; acc[3] += w * a.w;
        acc[4] += w * b.x; acc[5] += w * b.y; acc[6] += w * b.z; acc[7] += w * b.w;
        lg2_0 = leaky(s1k + s2[i0]);
    }
    if (h1) {
        int i1 = edge_list[k * EDGE_CAP + 64 + lane];
        float w = expf(leaky(sx[i1] + sek)) * node_inv[i1];
        const float4* wx4 = (const float4*)(WX + i1 * DH);
        float4 a = wx4[0], b = wx4[1];
        acc[0] += w * a.x; acc[1] += w * a.y; acc[2] += w * a.z; acc[3] += w * a.w;
        acc[4] += w * b.x; acc[5] += w * b.y; acc[6] += w * b.z; acc[7] += w * b.w;
        lg2_1 = leaky(s1k + s2[i1]);
    }
    #pragma unroll
    for (int d = 0; d < DH; d++) acc[d] = wave_reduce_sum(acc[d]);
    float m2 = wave_reduce_max(fmaxf(lg2_0, lg2_1));
    float e2 = (h0 ? expf(lg2_0 - m2) : 0.f) + (h1 ? expf(lg2_1 - m2) : 0.f);
    float sum2 = wave_reduce_sum(e2);
    if (lane == 0) {
        #pragma unroll
        for (int d = 0; d < DH; d++) {
            float en = elu(acc[d] + emptyX[d] * (1.0f / (float)M_EDGES));
            E_new[k * DH + d] = en;
            if (cnt == 0) atomicAdd(&emptyE[d], en);  // empty edge: uniform 1/N to all nodes
        }
        if (cnt > 0) { edge_m2[k] = m2; edge_inv2[k] = 1.f / sum2; }
    }
}

// Kernel 4: per-node gather; 8 lanes per node (one per dim).
__global__ __launch_bounds__(256) void node_gather_kernel(
    const int* __restrict__ node_cnt, const int* __restrict__ node_list,
    const float* __restrict__ s1, const float* __restrict__ s2,
    const float* __restrict__ edge_m2, const float* __restrict__ edge_inv2,
    const float* __restrict__ E_new, const float* __restrict__ emptyE,
    float* __restrict__ out) {
    int idx = blockIdx.x * blockDim.x + threadIdx.x;   // 65536 threads
    int i = idx >> 3, d = idx & 7;
    int cnt = node_cnt[i];
    float s2i = s2[i];
    float acc = emptyE[d] * (1.0f / (float)N_NODES);
    for (int e = 0; e < cnt; ++e) {
        int k = node_list[i * NODE_CAP + e];
        float w2 = expf(leaky(s1[k] + s2i) - edge_m2[k]) * edge_inv2[k];
        acc += w2 * E_new[k * DH + d];
    }
    out[i * DH + d] = elu(acc);
}

extern "C" void kernel_launch(void* const* d_in, const int* in_sizes, int n_in,
                              void* d_out, int out_size, void* d_ws, size_t ws_size,
                              hipStream_t stream) {
    const float* X  = (const float*)d_in[0];
    const float* E  = (const float*)d_in[1];
    const float* H  = (const float*)d_in[2];
    const float* W  = (const float*)d_in[3];
    const float* ax = (const float*)d_in[4];
    const float* ae = (const float*)d_in[5];
    float* out = (float*)d_out;

    float* ws = (float*)d_ws;
    // workspace layout (float offsets)
    float* WX        = ws + 0;        // 65536
    float* sx        = ws + 65536;    // 8192
    float* se        = ws + 73728;    // 2048
    float* s1        = ws + 75776;    // 2048
    float* s2        = ws + 77824;    // 8192
    float* node_inv  = ws + 86016;    // 8192
    float* E_new     = ws + 94208;    // 16384
    float* edge_m2   = ws + 110592;   // 2048
    float* edge_inv2 = ws + 112640;   // 2048
    int*   node_cnt  = (int*)(ws + 114688);   // 8192
    int*   node_list = (int*)(ws + 122880);   // 8192*32 = 262144
    int*   edge_list = (int*)(ws + 385024);   // 2048*128 = 262144
    // ---- zero region (cleared by proj tail blocks) ----
    int*   edge_cnt  = (int*)(ws + 647168);   // 2048
    float* emptyX    = ws + 649216;   // 8
    float* emptyE    = ws + 649224;   // 8
    // total 649232 floats = 2.48 MB

    proj_kernel<<<PROJ_BLOCKS + ZERO_BLOCKS, 256, 0, stream>>>(
        X, E, W, ax, ae, WX, sx, se, s1, s2, edge_cnt);
    node_scan_kernel<<<N_NODES / 4, 256, 0, stream>>>(
        H, WX, sx, se, node_cnt, node_list, node_inv,
        edge_cnt, edge_list, emptyX);
    edge_gather_kernel<<<M_EDGES / 4, 256, 0, stream>>>(
        edge_cnt, edge_list, WX, sx, se, s1, s2, node_inv, emptyX,
        E_new, edge_m2, edge_inv2, emptyE);
    node_gather_kernel<<<(N_NODES * DH) / 256, 256, 0, stream>>>(
        node_cnt, node_list, s1, s2, edge_m2, edge_inv2, E_new, emptyE, out);
}

// Round 6
// 133.402 us; speedup vs baseline: 1.1751x; 1.0546x over previous
//
#include <hip/hip_runtime.h>
#include <hip/hip_bf16.h>
#include <cfloat>
#include <math.h>

#define N_NODES 8192
#define M_EDGES 2048
#define D_IN    256
#define DH      8
#define NODE_CAP 32    // max edges per node; deg mean 8.2, std 2.9 -> 8.5 sigma margin
#define EDGE_CAP 128   // max nodes per edge; mean 32.8, std 5.7 -> 16 sigma margin
#define PROJ_BLOCKS ((N_NODES + M_EDGES) / 4)
#define ZERO_INTS (M_EDGES + 16)          // edge_cnt + emptyX + emptyE (contiguous)
#define ZERO_BLOCKS 9

__device__ __forceinline__ float wave_reduce_sum(float v) {
    #pragma unroll
    for (int m = 1; m < 64; m <<= 1) v += __shfl_xor(v, m, 64);
    return v;
}
__device__ __forceinline__ float wave_reduce_max(float v) {
    #pragma unroll
    for (int m = 1; m < 64; m <<= 1) v = fmaxf(v, __shfl_xor(v, m, 64));
    return v;
}
__device__ __forceinline__ float leaky(float t) { return t >= 0.f ? t : 0.2f * t; }
__device__ __forceinline__ float elu(float v) { return v > 0.f ? v : expm1f(v); }

// Kernel 1: WX = X@W (stored), WE = E@W (scores only), plus scalar scores.
// Tail blocks zero edge_cnt/emptyX/emptyE (no separate memset dispatch; consumers
// launch after the full grid retires).
__global__ __launch_bounds__(256) void proj_kernel(
    const float* __restrict__ X, const float* __restrict__ E,
    const float* __restrict__ W, const float* __restrict__ ax, const float* __restrict__ ae,
    float* __restrict__ WX,
    float* __restrict__ sx, float* __restrict__ se,
    float* __restrict__ s1, float* __restrict__ s2,
    int* __restrict__ zero_region) {
    if (blockIdx.x >= PROJ_BLOCKS) {
        int z = (blockIdx.x - PROJ_BLOCKS) * 256 + threadIdx.x;
        if (z < ZERO_INTS) zero_region[z] = 0;
        return;
    }
    int wave = (blockIdx.x * blockDim.x + threadIdx.x) >> 6;
    int lane = threadIdx.x & 63;
    bool isX = wave < N_NODES;
    int row = isX ? wave : wave - N_NODES;
    const float* src = isX ? (X + (size_t)row * D_IN) : (E + (size_t)row * D_IN);
    float4 x4 = ((const float4*)src)[lane];
    const float4* W4 = (const float4*)W;
    float4 w[8];
    #pragma unroll
    for (int j = 0; j < 8; j++) w[j] = W4[lane * 8 + j];   // W rows 4l..4l+3 (contiguous)
    const float* wf = (const float*)w;
    float wxd[DH];
    #pragma unroll
    for (int d = 0; d < DH; d++) {
        float p = x4.x * wf[d] + x4.y * wf[8 + d] + x4.z * wf[16 + d] + x4.w * wf[24 + d];
        wxd[d] = wave_reduce_sum(p);
    }
    if (lane == 0) {
        if (isX) {
            float a0 = 0.f, a1 = 0.f;
            #pragma unroll
            for (int d = 0; d < DH; d++) {
                WX[row * DH + d] = wxd[d];
                a0 += wxd[d] * ax[d];        // sx
                a1 += wxd[d] * ae[DH + d];   // s2
            }
            sx[row] = a0; s2[row] = a1;
        } else {
            float a0 = 0.f, a1 = 0.f;
            #pragma unroll
            for (int d = 0; d < DH; d++) {
                a0 += wxd[d] * ax[DH + d];   // se
                a1 += wxd[d] * ae[d];        // s1
            }
            se[row] = a0; s1[row] = a1;
        }
    }
}

// Kernel 2: per-node scan of H row (LDS-atomic compaction — measured faster than
// ballot compaction, r5 post-mortem). Builds node->edge list, per-node softmax
// denom (no max-sub: |logit|<~30, f32-safe), transposed edge lists (counter
// atomics only), empty-node accumulation.
__global__ __launch_bounds__(256) void node_scan_kernel(
    const float* __restrict__ H, const float* __restrict__ WX,
    const float* __restrict__ sx, const float* __restrict__ se,
    int* __restrict__ node_cnt, int* __restrict__ node_list,
    float* __restrict__ node_inv,
    int* __restrict__ edge_cnt, int* __restrict__ edge_list,
    float* __restrict__ emptyX) {
    __shared__ int s_cnt[4];
    __shared__ int s_list[4][NODE_CAP];
    int wv = threadIdx.x >> 6, lane = threadIdx.x & 63;
    int i = blockIdx.x * 4 + wv;
    if (lane == 0) s_cnt[wv] = 0;
    __syncthreads();
    const float4* Hrow = (const float4*)(H + (size_t)i * M_EDGES);
    float4 v[8];
    #pragma unroll
    for (int it = 0; it < 8; ++it) v[it] = Hrow[it * 64 + lane];   // all loads in flight
    #pragma unroll
    for (int it = 0; it < 8; ++it) {
        int c0 = (it * 64 + lane) * 4;
        if (v[it].x > 0.f) { int p = atomicAdd(&s_cnt[wv], 1); if (p < NODE_CAP) s_list[wv][p] = c0; }
        if (v[it].y > 0.f) { int p = atomicAdd(&s_cnt[wv], 1); if (p < NODE_CAP) s_list[wv][p] = c0 + 1; }
        if (v[it].z > 0.f) { int p = atomicAdd(&s_cnt[wv], 1); if (p < NODE_CAP) s_list[wv][p] = c0 + 2; }
        if (v[it].w > 0.f) { int p = atomicAdd(&s_cnt[wv], 1); if (p < NODE_CAP) s_list[wv][p] = c0 + 3; }
    }
    __syncthreads();
    int cnt = min(s_cnt[wv], NODE_CAP);
    if (cnt == 0) {
        // all-NEG_INF row -> uniform 1/M over every edge; accumulate WX[i]
        if (lane == 0) node_cnt[i] = 0;
        if (lane < DH) atomicAdd(&emptyX[lane], WX[i * DH + lane]);
        return;
    }
    float sxi = sx[i];
    int k = -1;
    float e = 0.f;
    if (lane < cnt) { k = s_list[wv][lane]; e = expf(leaky(sxi + se[k])); }
    float s = wave_reduce_sum(e);
    if (lane == 0) { node_cnt[i] = cnt; node_inv[i] = 1.f / s; }
    if (lane < cnt) {
        node_list[i * NODE_CAP + lane] = k;
        int p = atomicAdd(&edge_cnt[k], 1);
        if (p < EDGE_CAP) edge_list[k * EDGE_CAP + p] = i;
    }
}

// Kernel 3: per-edge gather. E_new[k] = elu(sum_i att[i,k]*WX[i] + emptyX/M).
// Also pass-2 softmax stats (m2_k, inv2_k) over the same member list.
__global__ __launch_bounds__(256) void edge_gather_kernel(
    const int* __restrict__ edge_cnt, const int* __restrict__ edge_list,
    const float* __restrict__ WX,
    const float* __restrict__ sx, const float* __restrict__ se,
    const float* __restrict__ s1, const float* __restrict__ s2,
    const float* __restrict__ node_inv,
    const float* __restrict__ emptyX,
    float* __restrict__ E_new, float* __restrict__ edge_m2, float* __restrict__ edge_inv2,
    float* __restrict__ emptyE) {
    int wv = threadIdx.x >> 6, lane = threadIdx.x & 63;
    int k = blockIdx.x * 4 + wv;
    int cnt = min(edge_cnt[k], EDGE_CAP);
    float sek = se[k], s1k = s1[k];
    float acc[DH];
    #pragma unroll
    for (int d = 0; d < DH; d++) acc[d] = 0.f;
    float lg2_0 = -FLT_MAX, lg2_1 = -FLT_MAX;
    bool h0 = lane < cnt, h1 = lane + 64 < cnt;
    if (h0) {
        int i0 = edge_list[k * EDGE_CAP + lane];
        float w = expf(leaky(sx[i0] + sek)) * node_inv[i0];
        const float4* wx4 = (const float4*)(WX + i0 * DH);
        float4 a = wx4[0], b = wx4[1];
        acc[0] += w * a.x; acc[1] += w * a.y; acc[2] += w * a.z; acc[3] += w * a.w;
        acc[4] += w * b.x; acc[5] += w * b.y; acc[6] += w * b.z; acc[7] += w * b.w;
        lg2_0 = leaky(s1k + s2[i0]);
    }
    if (h1) {
        int i1 = edge_list[k * EDGE_CAP + 64 + lane];
        float w = expf(leaky(sx[i1] + sek)) * node_inv[i1];
        const float4* wx4 = (const float4*)(WX + i1 * DH);
        float4 a = wx4[0], b = wx4[1];
        acc[0] += w * a.x; acc[1] += w * a.y; acc[2] += w * a.z; acc[3] += w * a.w;
        acc[4] += w * b.x; acc[5] += w * b.y; acc[6] += w * b.z; acc[7] += w * b.w;
        lg2_1 = leaky(s1k + s2[i1]);
    }
    #pragma unroll
    for (int d = 0; d < DH; d++) acc[d] = wave_reduce_sum(acc[d]);
    float m2 = wave_reduce_max(fmaxf(lg2_0, lg2_1));
    float e2 = (h0 ? expf(lg2_0 - m2) : 0.f) + (h1 ? expf(lg2_1 - m2) : 0.f);
    float sum2 = wave_reduce_sum(e2);
    if (lane == 0) {
        #pragma unroll
        for (int d = 0; d < DH; d++) {
            float en = elu(acc[d] + emptyX[d] * (1.0f / (float)M_EDGES));
            E_new[k * DH + d] = en;
            if (cnt == 0) atomicAdd(&emptyE[d], en);  // empty edge: uniform 1/N to all nodes
        }
        if (cnt > 0) { edge_m2[k] = m2; edge_inv2[k] = 1.f / sum2; }
    }
}

// Kernel 4: per-node gather; 8 lanes per node (one per dim).
__global__ __launch_bounds__(256) void node_gather_kernel(
    const int* __restrict__ node_cnt, const int* __restrict__ node_list,
    const float* __restrict__ s1, const float* __restrict__ s2,
    const float* __restrict__ edge_m2, const float* __restrict__ edge_inv2,
    const float* __restrict__ E_new, const float* __restrict__ emptyE,
    float* __restrict__ out) {
    int idx = blockIdx.x * blockDim.x + threadIdx.x;   // 65536 threads
    int i = idx >> 3, d = idx & 7;
    int cnt = node_cnt[i];
    float s2i = s2[i];
    float acc = emptyE[d] * (1.0f / (float)N_NODES);
    for (int e = 0; e < cnt; ++e) {
        int k = node_list[i * NODE_CAP + e];
        float w2 = expf(leaky(s1[k] + s2i) - edge_m2[k]) * edge_inv2[k];
        acc += w2 * E_new[k * DH + d];
    }
    out[i * DH + d] = elu(acc);
}

extern "C" void kernel_launch(void* const* d_in, const int* in_sizes, int n_in,
                              void* d_out, int out_size, void* d_ws, size_t ws_size,
                              hipStream_t stream) {
    const float* X  = (const float*)d_in[0];
    const float* E  = (const float*)d_in[1];
    const float* H  = (const float*)d_in[2];
    const float* W  = (const float*)d_in[3];
    const float* ax = (const float*)d_in[4];
    const float* ae = (const float*)d_in[5];
    float* out = (float*)d_out;

    float* ws = (float*)d_ws;
    // workspace layout (float offsets)
    float* WX        = ws + 0;        // 65536
    float* sx        = ws + 65536;    // 8192
    float* se        = ws + 73728;    // 2048
    float* s1        = ws + 75776;    // 2048
    float* s2        = ws + 77824;    // 8192
    float* node_inv  = ws + 86016;    // 8192
    float* E_new     = ws + 94208;    // 16384
    float* edge_m2   = ws + 110592;   // 2048
    float* edge_inv2 = ws + 112640;   // 2048
    int*   node_cnt  = (int*)(ws + 114688);   // 8192
    int*   node_list = (int*)(ws + 122880);   // 8192*32 = 262144
    int*   edge_list = (int*)(ws + 385024);   // 2048*128 = 262144
    // ---- zero region (cleared by proj tail blocks) ----
    int*   edge_cnt  = (int*)(ws + 647168);   // 2048
    float* emptyX    = ws + 649216;   // 8
    float* emptyE    = ws + 649224;   // 8
    // total 649232 floats = 2.48 MB

    proj_kernel<<<PROJ_BLOCKS + ZERO_BLOCKS, 256, 0, stream>>>(
        X, E, W, ax, ae, WX, sx, se, s1, s2, edge_cnt);
    node_scan_kernel<<<N_NODES / 4, 256, 0, stream>>>(
        H, WX, sx, se, node_cnt, node_list, node_inv,
        edge_cnt, edge_list, emptyX);
    edge_gather_kernel<<<M_EDGES / 4, 256, 0, stream>>>(
        edge_cnt, edge_list, WX, sx, se, s1, s2, node_inv, emptyX,
        E_new, edge_m2, edge_inv2, emptyE);
    node_gather_kernel<<<(N_NODES * DH) / 256, 256, 0, stream>>>(
        node_cnt, node_list, s1, s2, edge_m2, edge_inv2, E_new, emptyE, out);
}